// Round 2
// baseline (247.311 us; speedup 1.0000x reference)
//
#include <hip/hip_runtime.h>
#include <stdint.h>

// Shapes (fixed by the reference)
#define B_  4096
#define V_  5
#define D_  512
#define NN_ (B_ * V_)            // 20480 text rows

// p = exp((dot - 1)/T) = exp2(dot*C - C), C = log2(e)/T
#define C_EXP 20.609929155556620f   // 1.4426950408889634 / 0.07
#define M_SHIFT (1.0f / 0.07f)

typedef _Float16 half8   __attribute__((ext_vector_type(8)));
typedef float    floatx4 __attribute__((ext_vector_type(4)));

// async global->LDS DMA, 16B per lane.
// NOTE: direct addrspace casts (addrspacecast), NO integer truncation — the
// previous integer round-trip risked a wild LDS offset -> GPU fault.
__device__ __forceinline__ void load_lds16(const _Float16* g, _Float16* l) {
  __builtin_amdgcn_global_load_lds(
      (const __attribute__((address_space(1))) unsigned int*)g,
      (__attribute__((address_space(3))) unsigned int*)l,
      16, 0, 0);
}

// ---------------------------------------------------------------------------
// Kernel 1: fp32 -> f16 convert (img then txt, contiguous) + zero accumulators
// grid = 12288 x 256 threads, one float4 each (exact cover of 12,582,912 floats)
// ---------------------------------------------------------------------------
__global__ void cvt_kernel(const float* __restrict__ img, const float* __restrict__ txt,
                           _Float16* __restrict__ outH, float* __restrict__ acc) {
  int idx = blockIdx.x * 256 + threadIdx.x;
  if (idx < B_ + NN_ + 1) acc[idx] = 0.0f;   // row_sum + col_sum + pos_sum
  const int n_img4 = (B_ * D_) / 4;          // 524288
  float4 v;
  if (idx < n_img4) v = ((const float4*)img)[idx];
  else              v = ((const float4*)txt)[idx - n_img4];
  union { _Float16 h[4]; float2 f2; } u;
  u.h[0] = (_Float16)v.x; u.h[1] = (_Float16)v.y;
  u.h[2] = (_Float16)v.z; u.h[3] = (_Float16)v.w;
  ((float2*)outH)[idx] = u.f2;
}

// ---------------------------------------------------------------------------
// Kernel 2: possum = sum_{i,v} dot(img_i, txt_{i,v}) / T   (elementwise reduce)
// Runs after cvt (same stream) so the pos accumulator is already zeroed.
// ---------------------------------------------------------------------------
__global__ void pos_kernel(const float* __restrict__ img, const float* __restrict__ txt,
                           float* __restrict__ pos) {
  const int n4 = (NN_ * D_) / 4;             // 2,621,440 float4 groups
  int idx = blockIdx.x * 256 + threadIdx.x;
  float s = 0.0f;
  for (int i = idx; i < n4; i += gridDim.x * 256) {
    int k4  = i & 127;                       // D/4 = 128
    int row = i >> 7;                        // i*V + v
    int ii  = row / 5;                       // image index (magic-mul)
    float4 t = ((const float4*)txt)[i];
    float4 g = ((const float4*)img)[ii * 128 + k4];
    s += t.x * g.x + t.y * g.y + t.z * g.z + t.w * g.w;
  }
  for (int o = 32; o; o >>= 1) s += __shfl_xor(s, o);
  __shared__ float ls[4];
  int lane = threadIdx.x & 63, w = threadIdx.x >> 6;
  if (lane == 0) ls[w] = s;
  __syncthreads();
  if (threadIdx.x == 0)
    atomicAdd(pos, (ls[0] + ls[1] + ls[2] + ls[3]) * M_SHIFT);
}

// ---------------------------------------------------------------------------
// Kernel 3: fused GEMM + exp + row/col partial sums
// 128x128 tile, BK=32, 256 threads (4 waves, 2x2 of 64x64), 16x16x32 f16 MFMA
// grid = (32 m-tiles, 160 n-tiles); m fastest so a B-tile is shared by 32 blocks
// ---------------------------------------------------------------------------
__global__ __launch_bounds__(256, 3)
void gemm_kernel(const _Float16* __restrict__ Ah, const _Float16* __restrict__ Bh,
                 float* __restrict__ row_sum, float* __restrict__ col_sum) {
  __shared__ __align__(16) _Float16 As[128 * 32];
  __shared__ __align__(16) _Float16 Bs[128 * 32];
  const int tid  = threadIdx.x;
  const int lane = tid & 63;
  const int w    = tid >> 6;                 // wave 0..3
  const int wm   = w >> 1, wn = w & 1;       // 2x2 wave grid
  const int m0   = blockIdx.x * 128;
  const int n0   = blockIdx.y * 128;

  floatx4 acc[4][4] = {};

  // staging: wave w stages rows [w*32, w*32+32); each DMA covers 16 rows x 64B
  const int srow   = w * 32 + (lane >> 2);   // + 16 for the second DMA
  const int schunk = (lane & 3) * 8;         // halves (8 halves = 16B)
  const _Float16* gA = Ah + (m0 + srow) * D_ + schunk;
  const _Float16* gB = Bh + (n0 + srow) * D_ + schunk;
  _Float16* lA = As + (w * 32) * 32;         // wave-uniform LDS base
  _Float16* lB = Bs + (w * 32) * 32;

  const int fk = (lane >> 4) * 8;            // frag k-offset (A/B layout: k=(lane>>4)*8+j)
  const int fr = lane & 15;                  // frag m/n index (lane&15)

  for (int kt = 0; kt < 16; ++kt) {
    const int kg = kt * 32;
    load_lds16(gA + kg,            lA);
    load_lds16(gA + kg + 16 * D_,  lA + 16 * 32);
    load_lds16(gB + kg,            lB);
    load_lds16(gB + kg + 16 * D_,  lB + 16 * 32);
    __syncthreads();   // compiler emits vmcnt(0) drain before s_barrier

    half8 af[4], bf[4];
#pragma unroll
    for (int f = 0; f < 4; ++f) {
      af[f] = *(const half8*)(As + (wm * 64 + f * 16 + fr) * 32 + fk);
      bf[f] = *(const half8*)(Bs + (wn * 64 + f * 16 + fr) * 32 + fk);
    }
#pragma unroll
    for (int mf = 0; mf < 4; ++mf)
#pragma unroll
      for (int nf = 0; nf < 4; ++nf)
        acc[mf][nf] = __builtin_amdgcn_mfma_f32_16x16x32_f16(af[mf], bf[nf], acc[mf][nf], 0, 0, 0);
    __syncthreads();   // protect LDS before next stage
  }

  // Epilogue: p = exp2(dot*C - C); C/D layout: col=lane&15, row=(lane>>4)*4+reg
#pragma unroll
  for (int mf = 0; mf < 4; ++mf)
#pragma unroll
    for (int nf = 0; nf < 4; ++nf)
#pragma unroll
      for (int r = 0; r < 4; ++r)
        acc[mf][nf][r] = exp2f(acc[mf][nf][r] * C_EXP - C_EXP);

  // column sums over this wave's 64 rows
  float cs[4];
#pragma unroll
  for (int nf = 0; nf < 4; ++nf) {
    float s = 0.0f;
#pragma unroll
    for (int mf = 0; mf < 4; ++mf)
      s += acc[mf][nf][0] + acc[mf][nf][1] + acc[mf][nf][2] + acc[mf][nf][3];
    s += __shfl_xor(s, 16);
    s += __shfl_xor(s, 32);
    cs[nf] = s;
  }
  {
    int g = lane >> 4;                        // lane group g holds frag g's sums
    float v = (g == 0) ? cs[0] : (g == 1) ? cs[1] : (g == 2) ? cs[2] : cs[3];
    atomicAdd(&col_sum[n0 + wn * 64 + (g << 4) + (lane & 15)], v);
  }

  // row sums over this wave's 64 cols
#pragma unroll
  for (int mf = 0; mf < 4; ++mf) {
    floatx4 t = acc[mf][0] + acc[mf][1] + acc[mf][2] + acc[mf][3];
#pragma unroll
    for (int r = 0; r < 4; ++r) {
      float s = t[r];
      s += __shfl_xor(s, 1); s += __shfl_xor(s, 2);
      s += __shfl_xor(s, 4); s += __shfl_xor(s, 8);
      t[r] = s;
    }
    if ((lane & 15) < 4) {                    // 16 lanes cover 16 rows of this m-frag
      int q = lane & 3;
      float v = (q == 0) ? t[0] : (q == 1) ? t[1] : (q == 2) ? t[2] : t[3];
      atomicAdd(&row_sum[m0 + wm * 64 + mf * 16 + ((lane >> 4) << 2) + q], v);
    }
  }
}

// ---------------------------------------------------------------------------
// Kernel 4: loss = M + 0.5*(mean log rowsum + mean log colsum - 2*pos/(BV))
// ---------------------------------------------------------------------------
__global__ void finish_kernel(const float* __restrict__ acc, float* __restrict__ out) {
  int tid = threadIdx.x;                     // single block, 256 threads
  float sA = 0.0f, sB = 0.0f;
  for (int i = tid; i < B_;  i += 256) sA += logf(acc[i]);
  for (int i = tid; i < NN_; i += 256) sB += logf(acc[B_ + i]);
  float s = sA * (1.0f / B_) + sB * (1.0f / NN_);
  for (int o = 32; o; o >>= 1) s += __shfl_xor(s, o);
  __shared__ float ls[4];
  int lane = tid & 63, w = tid >> 6;
  if (lane == 0) ls[w] = s;
  __syncthreads();
  if (tid == 0) {
    float tot = ls[0] + ls[1] + ls[2] + ls[3];
    float pos = acc[B_ + NN_];
    out[0] = M_SHIFT + 0.5f * (tot - 2.0f * pos / (float)NN_);
  }
}

// ---------------------------------------------------------------------------
extern "C" void kernel_launch(void* const* d_in, const int* in_sizes, int n_in,
                              void* d_out, int out_size, void* d_ws, size_t ws_size,
                              hipStream_t stream) {
  const float* img = (const float*)d_in[0];   // (4096, 512) fp32
  const float* txt = (const float*)d_in[1];   // (4096, 5, 512) fp32

  // workspace layout: [ img_f16 | txt_f16 | row_sum(4096) col_sum(20480) pos(1) ]
  const size_t halfBytes = (size_t)(B_ * D_ + NN_ * D_) * 2;      // 25,165,824
  const size_t needBytes = halfBytes + (size_t)(B_ + NN_ + 1) * 4;
  if (ws_size < needBytes) return;            // fail loudly (absmax), don't fault

  _Float16* Ah  = (_Float16*)d_ws;            // B*D halves
  _Float16* Bh  = Ah + B_ * D_;               // NN*D halves
  float* acc    = (float*)((char*)d_ws + halfBytes);
  float* row_s  = acc;
  float* col_s  = acc + B_;
  float* pos    = acc + B_ + NN_;

  cvt_kernel   <<<12288, 256, 0, stream>>>(img, txt, Ah, acc);
  pos_kernel   <<<1280, 256, 0, stream>>>(img, txt, pos);
  gemm_kernel  <<<dim3(32, 160), 256, 0, stream>>>(Ah, Bh, row_s, col_s);
  finish_kernel<<<1, 256, 0, stream>>>(acc, (float*)d_out);
}